// Round 1
// 178.556 us; speedup vs baseline: 1.0512x; 1.0512x over previous
//
#include <hip/hip_runtime.h>

#define BATCH 32
#define NDIM 512
#define LNUM 8
#define KDIM 8

// per-batch workspace layout (float offsets)
#define WS_PM     0        // int[512]  posmap: node -> pos in S, or -1
#define WS_S      512      // int[64]   (slot kept for layout stability; unused)
#define WS_ACT    640      // float[512] active mask
#define WS_W      1152     // float[64*64]
#define WS_B2     5248     // float[64*64] B2 = W A_SS W^T
#define WS_C2     9344     // float[64*64] C2 = W^T D_SS W
#define WS_RA     13440    // float[64*512]  RA[m][j]
#define WS_RD     46208    // float[64*512]  RD[q][j]
#define WS_RAT    78976    // float[512*64]  RAT[j][m] = RA[m][j]
#define WS_RDT    111744   // float[512*64]  RDT[j][q] = RD[q][j]
#define WS_STRIDE 144512   // ~18.5 MB total for 32 batches

#define LSTR 65
typedef float f4 __attribute__((ext_vector_type(4)));

// ---------------------------------------------------------------------------
// k_prep: grid (BATCH, 9). Every block redundantly rebuilds the tiny setup
// (posmap/S/act + 8-step W chain, ~5us) in LDS — this removes the serial
// 32-block k_small stage from the critical path entirely.
//   y = 0..7 : compute RA/RD for 64-column chunk j0 = y*64 (both layouts)
//   y = 8    : compute B2 = W A_SS W^T, C2 = W^T D_SS W; write posmap/act/W
__global__ __launch_bounds__(256) void k_prep(
    const float* __restrict__ A, const float* __restrict__ O,
    const int* __restrict__ indices, const int* __restrict__ wavelet,
    float* __restrict__ ws)
{
    const int b  = blockIdx.x;
    const int cy = blockIdx.y;           // 0..8
    const int tid = threadIdx.x;
    float* base = ws + (size_t)b * WS_STRIDE;

    __shared__ float Wl[64*LSTR];
    __shared__ float Buf1[64*LSTR];      // AS (chunk) / P1 (y==8)
    __shared__ float Buf2[64*LSTR];      // RAt (chunk) / P2 (y==8)
    __shared__ float Buf3[64*LSTR];      // W-chain temp / B2 (y==8)
    __shared__ int   pml[NDIM];
    __shared__ float actl[NDIM];
    __shared__ float actS[64];
    __shared__ int   idxsh[64];
    __shared__ int   Ssh[64];
    __shared__ int   prow[KDIM];
    __shared__ float Oall[LNUM*KDIM*KDIM];
    __shared__ int   s_sh;

    // ---- setup (identical to old k_small, LDS-only) ----
    for (int t = tid; t < LNUM*KDIM*KDIM; t += 256) {
        int l = t >> 6, k = t & 63;
        Oall[t] = O[((size_t)l*BATCH + b)*(KDIM*KDIM) + k];
    }
    if (tid < 64) idxsh[tid] = indices[b*64 + tid];
    for (int n = tid; n < NDIM; n += 256) { pml[n] = -1; actl[n] = 1.f; }
    __syncthreads();

    if (tid < 64) {
        int n = idxsh[tid];
        bool first = true;
        for (int t = 0; t < tid; ++t) if (idxsh[t] == n) first = false;
        unsigned long long m = __ballot(first);
        int rank = __popcll(m & ((1ull << tid) - 1ull));
        if (first) { pml[n] = rank; Ssh[rank] = n; }
        if (tid == 0) s_sh = (int)__popcll(m);
    }
    if (tid >= 64 && tid < 64 + LNUM) {
        actl[wavelet[b*LNUM + (tid - 64)]] = 0.f;
    }
    __syncthreads();
    const int s = s_sh;
    if (tid < 64 && tid >= s) Ssh[tid] = 0;
    __syncthreads();
    if (tid < 64) actS[tid] = actl[Ssh[tid]];

    // ---- W chain (redundant per block; cheap) ----
    for (int t = tid; t < 4096; t += 256) {
        int rr = t >> 6, cc = t & 63;
        Wl[rr*LSTR + cc] = (rr == cc && rr < s) ? 1.f : 0.f;
    }
    __syncthreads();
    for (int l = 0; l < LNUM; ++l) {
        if (tid < KDIM) prow[tid] = pml[idxsh[l*KDIM + tid]];
        __syncthreads();
        for (int t = tid; t < KDIM*64; t += 256) {
            int i = t >> 6, c = t & 63;
            float acc = 0.f;
            #pragma unroll
            for (int j = 0; j < KDIM; ++j)
                acc += Oall[l*64 + i*KDIM + j] * Wl[prow[j]*LSTR + c];
            Buf3[t] = acc;
        }
        __syncthreads();
        for (int t = tid; t < KDIM*64; t += 256) {
            int i = t >> 6, c = t & 63;
            Wl[prow[i]*LSTR + c] = Buf3[t];
        }
        __syncthreads();
    }

    if (cy < 8) {
        // ================= chunk path: RA/RD for columns j0..j0+63 =========
        const int j0 = cy * 64;
        float* AS  = Buf1;               // stride 64
        float* RAt = Buf2;               // stride 64
        float* g_RA  = base + WS_RA;
        float* g_RD  = base + WS_RD;
        float* g_RAT = base + WS_RAT;
        float* g_RDT = base + WS_RDT;

        // gather AS[n][c] = A[b][S[n]][j0+c]
        for (int t = tid; t < 1024; t += 256) {
            int n = t >> 4, cc = (t & 15) * 4;
            f4 v = ((const f4*)(A + ((size_t)b*NDIM + Ssh[n])*NDIM + j0))[t & 15];
            AS[n*64 + cc]   = v.x; AS[n*64 + cc+1] = v.y;
            AS[n*64 + cc+2] = v.z; AS[n*64 + cc+3] = v.w;
        }
        __syncthreads();

        const int g = tid >> 6;
        const int j = tid & 63;
        float racc[16];

        // RA[m][j] = sum_n W[m][n] * AS[n][j]
        #pragma unroll
        for (int k = 0; k < 16; ++k) racc[k] = 0.f;
        for (int n = 0; n < 64; ++n) {
            float av = AS[n*64 + j];
            #pragma unroll
            for (int k = 0; k < 16; ++k) racc[k] += Wl[(g*16 + k)*LSTR + n] * av;
        }
        #pragma unroll
        for (int k = 0; k < 16; ++k) {
            RAt[(g*16 + k)*64 + j] = racc[k];
            g_RA[(g*16 + k)*NDIM + j0 + j] = racc[k];
        }
        {
            f4* dst = (f4*)(g_RAT + (size_t)(j0 + j)*64 + g*16);
            #pragma unroll
            for (int q = 0; q < 4; ++q) {
                f4 v = { racc[4*q], racc[4*q+1], racc[4*q+2], racc[4*q+3] };
                dst[q] = v;
            }
        }
        __syncthreads();

        // RD[q][j] = actj * sum_n W[n][q] * actS[n] * RAt[n][j]
        #pragma unroll
        for (int k = 0; k < 16; ++k) racc[k] = 0.f;
        for (int n = 0; n < 64; ++n) {
            float dt = actS[n] * RAt[n*64 + j];
            #pragma unroll
            for (int k = 0; k < 16; ++k) racc[k] += Wl[n*LSTR + g*16 + k] * dt;
        }
        const float aj = actl[j0 + j];
        #pragma unroll
        for (int k = 0; k < 16; ++k) {
            float rd = racc[k] * aj;
            racc[k] = rd;
            g_RD[(g*16 + k)*NDIM + j0 + j] = rd;
        }
        {
            f4* dst = (f4*)(g_RDT + (size_t)(j0 + j)*64 + g*16);
            #pragma unroll
            for (int q = 0; q < 4; ++q) {
                f4 v = { racc[4*q], racc[4*q+1], racc[4*q+2], racc[4*q+3] };
                dst[q] = v;
            }
        }
    } else {
        // ================= y == 8: B2/C2 + setup globals ====================
        {
            int*   g_posmap = (int*)(base + WS_PM);
            float* g_act    = base + WS_ACT;
            float* g_W      = base + WS_W;
            for (int n = tid; n < NDIM; n += 256) { g_posmap[n] = pml[n]; g_act[n] = actl[n]; }
            for (int t = tid; t < 4096; t += 256) g_W[t] = Wl[(t>>6)*LSTR + (t&63)];
        }

        // gather A_SS -> Buf1
        for (int t = tid; t < 4096; t += 256) {
            int n = t >> 6, m = t & 63;
            Buf1[n*LSTR + m] = A[((size_t)b*NDIM + Ssh[n])*NDIM + Ssh[m]];
        }
        __syncthreads();

        const int w = tid >> 6;
        const int ln = tid & 63;
        float acc[16];

        // T = W * A_SS -> Buf2
        #pragma unroll
        for (int k = 0; k < 16; ++k) acc[k] = 0.f;
        for (int n = 0; n < 64; ++n) {
            float as = Buf1[n*LSTR + ln];
            #pragma unroll
            for (int k = 0; k < 16; ++k) acc[k] += Wl[(w*16 + k)*LSTR + n] * as;
        }
        #pragma unroll
        for (int k = 0; k < 16; ++k) Buf2[(w*16 + k)*LSTR + ln] = acc[k];
        __syncthreads();

        // B2 = T * W^T -> Buf3
        #pragma unroll
        for (int k = 0; k < 16; ++k) acc[k] = 0.f;
        for (int m = 0; m < 64; ++m) {
            float wv = Wl[ln*LSTR + m];
            #pragma unroll
            for (int k = 0; k < 16; ++k) acc[k] += Buf2[(w*16 + k)*LSTR + m] * wv;
        }
        #pragma unroll
        for (int k = 0; k < 16; ++k) Buf3[(w*16 + k)*LSTR + ln] = acc[k];
        __syncthreads();
        {
            float* g_B2 = base + WS_B2;
            for (int t = tid; t < 4096; t += 256) g_B2[t] = Buf3[(t>>6)*LSTR + (t&63)];
        }

        // D_SS = mask .* B2 -> Buf1
        for (int t = tid; t < 4096; t += 256) {
            int n = t >> 6, m = t & 63;
            float mv = (Ssh[n] == Ssh[m]) ? 1.f : actS[n]*actS[m];
            Buf1[n*LSTR + m] = mv * Buf3[n*LSTR + m];
        }
        __syncthreads();

        // T2 = W^T * D_SS -> Buf2
        #pragma unroll
        for (int k = 0; k < 16; ++k) acc[k] = 0.f;
        for (int n = 0; n < 64; ++n) {
            float dv = Buf1[n*LSTR + ln];
            #pragma unroll
            for (int k = 0; k < 16; ++k) acc[k] += Wl[n*LSTR + (w*16 + k)] * dv;
        }
        #pragma unroll
        for (int k = 0; k < 16; ++k) Buf2[(w*16 + k)*LSTR + ln] = acc[k];
        __syncthreads();

        // C2 = T2 * W
        #pragma unroll
        for (int k = 0; k < 16; ++k) acc[k] = 0.f;
        for (int m = 0; m < 64; ++m) {
            float wv = Wl[m*LSTR + ln];
            #pragma unroll
            for (int k = 0; k < 16; ++k) acc[k] += Buf2[(w*16 + k)*LSTR + m] * wv;
        }
        {
            float* g_C2 = base + WS_C2;
            #pragma unroll
            for (int k = 0; k < 16; ++k) g_C2[(w*16 + k)*64 + ln] = acc[k];
        }
    }
}

// ---------------------------------------------------------------------------
// k_big: zero-LDS float4 pass over (b,i,j) writing A_rec, right, D.
// Streaming traffic (A read-once, out write-once) uses non-temporal hints so
// the L1/L2 stay reserved for the reused RAT/RDT/posmap/act/B2/C2 data.
__global__ __launch_bounds__(256) void k_big(const float* __restrict__ A,
                                             const float* __restrict__ ws,
                                             float* __restrict__ out)
{
    const int b = blockIdx.y;
    const int rh = threadIdx.x >> 7;          // 2 rows per block
    const int lane = threadIdx.x & 127;       // 128 float4s per row
    const int i = blockIdx.x*2 + rh;
    const int j0 = lane*4;

    const float* base = ws + (size_t)b * WS_STRIDE;
    const int*   posmap = (const int*)(base + WS_PM);
    const float* act = base + WS_ACT;
    const float* g_W  = base + WS_W;
    const float* g_B2 = base + WS_B2;
    const float* g_C2 = base + WS_C2;
    const float* RA  = base + WS_RA;
    const float* RD  = base + WS_RD;
    const float* RAT = base + WS_RAT;
    const float* RDT = base + WS_RDT;

    const int pi = posmap[i];
    const float acti = act[i];
    const size_t rowoff = ((size_t)b*NDIM + i)*NDIM;
    const size_t seg = (size_t)BATCH*NDIM*NDIM;

    int4   p4  = ((const int4*)posmap)[lane];
    float4 aj4 = ((const float4*)act)[lane];
    int   pm[4] = {p4.x, p4.y, p4.z, p4.w};
    float aj[4] = {aj4.x, aj4.y, aj4.z, aj4.w};

    float a[4], arec[4], dv[4], rv[4];

    if (pi < 0) {
        const float* rat = RAT + (size_t)i*64;   // 256 B, L1-hot per half-block
        const float* rdt = RDT + (size_t)i*64;
        f4 v = __builtin_nontemporal_load((const f4*)(A + rowoff) + lane);
        a[0]=v.x; a[1]=v.y; a[2]=v.z; a[3]=v.w;
        #pragma unroll
        for (int c = 0; c < 4; ++c) {
            int pj = pm[c];
            if (pj >= 0) a[c] = rat[pj];
            float mv = (i == j0 + c) ? 1.f : acti * aj[c];
            dv[c] = a[c] * mv;
            arec[c] = (pj < 0) ? dv[c] : rdt[pj];
            rv[c] = (i == j0 + c) ? 1.f : 0.f;
        }
    } else {
        f4 v = ((const f4*)(RA + (size_t)pi*NDIM))[lane];
        f4 w = ((const f4*)(RD + (size_t)pi*NDIM))[lane];
        a[0]=v.x; a[1]=v.y; a[2]=v.z; a[3]=v.w;
        arec[0]=w.x; arec[1]=w.y; arec[2]=w.z; arec[3]=w.w;
        #pragma unroll
        for (int c = 0; c < 4; ++c) {
            int pj = pm[c];
            if (pj >= 0) {
                a[c]    = g_B2[pi*64 + pj];
                arec[c] = g_C2[pi*64 + pj];
                rv[c]   = g_W[pi*64 + pj];
            } else {
                rv[c] = 0.f;
            }
            float mv = (i == j0 + c) ? 1.f : acti * aj[c];
            dv[c] = a[c] * mv;
        }
    }

    f4 o0; o0.x = arec[0]; o0.y = arec[1]; o0.z = arec[2]; o0.w = arec[3];
    f4 o1; o1.x = rv[0];   o1.y = rv[1];   o1.z = rv[2];   o1.w = rv[3];
    f4 o2; o2.x = dv[0];   o2.y = dv[1];   o2.z = dv[2];   o2.w = dv[3];
    __builtin_nontemporal_store(o0, (f4*)(out + rowoff) + lane);
    __builtin_nontemporal_store(o1, (f4*)(out + seg + rowoff) + lane);
    __builtin_nontemporal_store(o2, (f4*)(out + 2*seg + rowoff) + lane);
}

extern "C" void kernel_launch(void* const* d_in, const int* in_sizes, int n_in,
                              void* d_out, int out_size, void* d_ws, size_t ws_size,
                              hipStream_t stream) {
    const float* A       = (const float*)d_in[0];
    const float* O       = (const float*)d_in[1];
    const int*   indices = (const int*)d_in[2];
    const int*   wavelet = (const int*)d_in[3];
    float* ws  = (float*)d_ws;   // needs ~18.5 MB
    float* out = (float*)d_out;

    k_prep<<<dim3(BATCH, 9), 256, 0, stream>>>(A, O, indices, wavelet, ws);
    k_big <<<dim3(NDIM/2, BATCH), 256, 0, stream>>>(A, ws, out);
}

// Round 2
// 175.761 us; speedup vs baseline: 1.0679x; 1.0159x over previous
//
#include <hip/hip_runtime.h>

#define BATCH 32
#define NDIM 512
#define LNUM 8
#define KDIM 8

// per-batch workspace layout (float offsets)
#define WS_PM     0        // int[512]  posmap: node -> pos in S, or -1
#define WS_S      512      // int[64]   (slot kept for layout stability; unused)
#define WS_ACT    640      // float[512] active mask
#define WS_W      1152     // float[64*64]
#define WS_B2     5248     // float[64*64] B2 = W A_SS W^T
#define WS_C2     9344     // float[64*64] C2 = W^T D_SS W
#define WS_RA     13440    // float[64*512]  RA[m][j]
#define WS_RD     46208    // float[64*512]  RD[q][j]
#define WS_RAT    78976    // float[512*64]  RAT[j][m] = RA[m][j]
#define WS_RDT    111744   // float[512*64]  RDT[j][q] = RD[q][j]
#define WS_STRIDE 144512   // ~18.5 MB total for 32 batches

#define LSTR 65
typedef float f4 __attribute__((ext_vector_type(4)));

// ---------------------------------------------------------------------------
// k_prep: grid (BATCH, 9).
//   y = 0..7 : RA/RD for 64-column chunk j0 = y*64 (both layouts)
//   y = 8    : B2 = W A_SS W^T, C2 = W^T D_SS W; posmap/act/W globals
//
// Barrier-minimized setup: the W-chain update W[prow_i][c] = sum_j O[i][j]
// W[prow_j][c] is COLUMN-LOCAL (lane c touches only column c), so wave 0
// runs ballot + W-init + the whole 8-level chain with no block barriers,
// while waves 1-3 concurrently gather the A tile (needs only Ssh, ready
// after barrier #2a). 4 barriers total on the chunk path (was ~27).
__global__ __launch_bounds__(256) void k_prep(
    const float* __restrict__ A, const float* __restrict__ O,
    const int* __restrict__ indices, const int* __restrict__ wavelet,
    float* __restrict__ ws)
{
    const int b  = blockIdx.x;
    const int cy = blockIdx.y;           // 0..8
    const int tid = threadIdx.x;
    float* base = ws + (size_t)b * WS_STRIDE;

    __shared__ float Wl[64*LSTR];
    __shared__ __align__(16) float Buf1[64*LSTR];   // AS (chunk, stride 64) / P1 (y==8, LSTR)
    __shared__ __align__(16) float Buf2[64*LSTR];   // RAt (chunk, stride 64) / P2 (y==8)
    __shared__ __align__(16) float Buf3[64*LSTR];   // B2 temp (y==8)
    __shared__ int   pml[NDIM];
    __shared__ float actl[NDIM];
    __shared__ float actS[64];
    __shared__ int   idxsh[64];
    __shared__ int   Ssh[64];
    __shared__ float Oall[LNUM*KDIM*KDIM];

    // ---- block-wide staging (no deps) ----
    for (int t = tid; t < LNUM*KDIM*KDIM; t += 256) {
        int l = t >> 6, k = t & 63;
        Oall[t] = O[((size_t)l*BATCH + b)*(KDIM*KDIM) + k];
    }
    if (tid < 64) idxsh[tid] = indices[b*64 + tid];
    for (int n = tid; n < NDIM; n += 256) { pml[n] = -1; actl[n] = 1.f; }
    __syncthreads();                                        // #1

    const int wv = tid >> 6;
    const int ln = tid & 63;
    int s_reg = 0;

    if (wv == 0) {
        // ballot dedup (wave 0 only; all 64 lanes active)
        int n = idxsh[ln];
        bool first = true;
        for (int t = 0; t < ln; ++t) if (idxsh[t] == n) first = false;
        unsigned long long m = __ballot(first);
        int rank = __popcll(m & ((1ull << ln) - 1ull));
        s_reg = (int)__popcll(m);
        if (first) { pml[n] = rank; Ssh[rank] = n; }
        if (ln >= s_reg) Ssh[ln] = 0;                        // pad (write-only, no cross-lane read)
        if (ln < LNUM) actl[wavelet[b*LNUM + ln]] = 0.f;
    }
    __syncthreads();                                        // #2a: Ssh/pml/actl visible

    if (wv == 0) {
        // actS (cross-lane Ssh reads now safe)
        actS[ln] = actl[Ssh[ln]];
        // W init: lane ln owns column ln
        for (int rr = 0; rr < 64; ++rr)
            Wl[rr*LSTR + ln] = (rr == ln && rr < s_reg) ? 1.f : 0.f;
        // 8-level chain, column-local, zero barriers
        for (int l = 0; l < LNUM; ++l) {
            int pr[KDIM];
            float wcol[KDIM], accv[KDIM];
            #pragma unroll
            for (int j = 0; j < KDIM; ++j) pr[j] = pml[idxsh[l*KDIM + j]];
            #pragma unroll
            for (int j = 0; j < KDIM; ++j) wcol[j] = Wl[pr[j]*LSTR + ln];
            #pragma unroll
            for (int i = 0; i < KDIM; ++i) {
                float a = 0.f;
                #pragma unroll
                for (int j = 0; j < KDIM; ++j)
                    a += Oall[l*64 + i*KDIM + j] * wcol[j];
                accv[i] = a;
            }
            #pragma unroll
            for (int i = 0; i < KDIM; ++i) Wl[pr[i]*LSTR + ln] = accv[i];
        }
    } else {
        // waves 1-3: gather A tile concurrently with the chain (needs Ssh only)
        if (cy < 8) {
            const int j0 = cy * 64;
            for (int t = tid - 64; t < 1024; t += 192) {
                int n = t >> 4, cc = t & 15;
                f4 v = ((const f4*)(A + ((size_t)b*NDIM + Ssh[n])*NDIM + j0))[cc];
                ((f4*)(Buf1 + n*64))[cc] = v;               // AS, stride 64
            }
        } else {
            for (int t = tid - 64; t < 4096; t += 192) {
                int n = t >> 6, mm = t & 63;
                Buf1[n*LSTR + mm] = A[((size_t)b*NDIM + Ssh[n])*NDIM + Ssh[mm]];
            }
            int*   g_posmap = (int*)(base + WS_PM);
            float* g_act    = base + WS_ACT;
            for (int n = tid - 64; n < NDIM; n += 192) {
                g_posmap[n] = pml[n]; g_act[n] = actl[n];
            }
        }
    }
    __syncthreads();                                        // #2b: Wl + A tile + actS ready

    if (cy < 8) {
        // ================= chunk path: RA/RD for columns j0..j0+63 =========
        const int j0 = cy * 64;
        float* AS  = Buf1;               // stride 64
        float* RAt = Buf2;               // stride 64
        float* g_RA  = base + WS_RA;
        float* g_RD  = base + WS_RD;
        float* g_RAT = base + WS_RAT;
        float* g_RDT = base + WS_RDT;

        const int g = wv;
        const int j = ln;
        float racc[16];

        // RA[m][j] = sum_n W[m][n] * AS[n][j]
        #pragma unroll
        for (int k = 0; k < 16; ++k) racc[k] = 0.f;
        for (int n = 0; n < 64; ++n) {
            float av = AS[n*64 + j];
            #pragma unroll
            for (int k = 0; k < 16; ++k) racc[k] += Wl[(g*16 + k)*LSTR + n] * av;
        }
        #pragma unroll
        for (int k = 0; k < 16; ++k) {
            RAt[(g*16 + k)*64 + j] = racc[k];
            g_RA[(g*16 + k)*NDIM + j0 + j] = racc[k];
        }
        {
            f4* dst = (f4*)(g_RAT + (size_t)(j0 + j)*64 + g*16);
            #pragma unroll
            for (int q = 0; q < 4; ++q) {
                f4 v = { racc[4*q], racc[4*q+1], racc[4*q+2], racc[4*q+3] };
                dst[q] = v;
            }
        }
        __syncthreads();                                    // #3

        // RD[q][j] = actj * sum_n W[n][q] * actS[n] * RAt[n][j]
        #pragma unroll
        for (int k = 0; k < 16; ++k) racc[k] = 0.f;
        for (int n = 0; n < 64; ++n) {
            float dt = actS[n] * RAt[n*64 + j];
            #pragma unroll
            for (int k = 0; k < 16; ++k) racc[k] += Wl[n*LSTR + g*16 + k] * dt;
        }
        const float aj = actl[j0 + j];
        #pragma unroll
        for (int k = 0; k < 16; ++k) {
            float rd = racc[k] * aj;
            racc[k] = rd;
            g_RD[(g*16 + k)*NDIM + j0 + j] = rd;
        }
        {
            f4* dst = (f4*)(g_RDT + (size_t)(j0 + j)*64 + g*16);
            #pragma unroll
            for (int q = 0; q < 4; ++q) {
                f4 v = { racc[4*q], racc[4*q+1], racc[4*q+2], racc[4*q+3] };
                dst[q] = v;
            }
        }
    } else {
        // ================= y == 8: B2/C2 + W global ========================
        {
            float* g_W = base + WS_W;
            for (int t = tid; t < 4096; t += 256) g_W[t] = Wl[(t>>6)*LSTR + (t&63)];
        }

        const int w = wv;
        float acc[16];

        // T = W * A_SS -> Buf2
        #pragma unroll
        for (int k = 0; k < 16; ++k) acc[k] = 0.f;
        for (int n = 0; n < 64; ++n) {
            float as = Buf1[n*LSTR + ln];
            #pragma unroll
            for (int k = 0; k < 16; ++k) acc[k] += Wl[(w*16 + k)*LSTR + n] * as;
        }
        #pragma unroll
        for (int k = 0; k < 16; ++k) Buf2[(w*16 + k)*LSTR + ln] = acc[k];
        __syncthreads();

        // B2 = T * W^T -> Buf3
        #pragma unroll
        for (int k = 0; k < 16; ++k) acc[k] = 0.f;
        for (int m = 0; m < 64; ++m) {
            float wvv = Wl[ln*LSTR + m];
            #pragma unroll
            for (int k = 0; k < 16; ++k) acc[k] += Buf2[(w*16 + k)*LSTR + m] * wvv;
        }
        #pragma unroll
        for (int k = 0; k < 16; ++k) Buf3[(w*16 + k)*LSTR + ln] = acc[k];
        __syncthreads();
        {
            float* g_B2 = base + WS_B2;
            for (int t = tid; t < 4096; t += 256) g_B2[t] = Buf3[(t>>6)*LSTR + (t&63)];
        }

        // D_SS = mask .* B2 -> Buf1
        for (int t = tid; t < 4096; t += 256) {
            int n = t >> 6, m = t & 63;
            float mv = (Ssh[n] == Ssh[m]) ? 1.f : actS[n]*actS[m];
            Buf1[n*LSTR + m] = mv * Buf3[n*LSTR + m];
        }
        __syncthreads();

        // T2 = W^T * D_SS -> Buf2
        #pragma unroll
        for (int k = 0; k < 16; ++k) acc[k] = 0.f;
        for (int n = 0; n < 64; ++n) {
            float dv = Buf1[n*LSTR + ln];
            #pragma unroll
            for (int k = 0; k < 16; ++k) acc[k] += Wl[n*LSTR + (w*16 + k)] * dv;
        }
        #pragma unroll
        for (int k = 0; k < 16; ++k) Buf2[(w*16 + k)*LSTR + ln] = acc[k];
        __syncthreads();

        // C2 = T2 * W
        #pragma unroll
        for (int k = 0; k < 16; ++k) acc[k] = 0.f;
        for (int m = 0; m < 64; ++m) {
            float wvv = Wl[m*LSTR + ln];
            #pragma unroll
            for (int k = 0; k < 16; ++k) acc[k] += Buf2[(w*16 + k)*LSTR + m] * wvv;
        }
        {
            float* g_C2 = base + WS_C2;
            #pragma unroll
            for (int k = 0; k < 16; ++k) g_C2[(w*16 + k)*64 + ln] = acc[k];
        }
    }
}

// ---------------------------------------------------------------------------
// k_big: zero-LDS float4 pass over (b,i,j) writing A_rec, right, D.
// Streaming traffic (A read-once, out write-once) uses non-temporal hints so
// the L1/L2 stay reserved for the reused RAT/RDT/posmap/act/B2/C2 data.
__global__ __launch_bounds__(256) void k_big(const float* __restrict__ A,
                                             const float* __restrict__ ws,
                                             float* __restrict__ out)
{
    const int b = blockIdx.y;
    const int rh = threadIdx.x >> 7;          // 2 rows per block
    const int lane = threadIdx.x & 127;       // 128 float4s per row
    const int i = blockIdx.x*2 + rh;
    const int j0 = lane*4;

    const float* base = ws + (size_t)b * WS_STRIDE;
    const int*   posmap = (const int*)(base + WS_PM);
    const float* act = base + WS_ACT;
    const float* g_W  = base + WS_W;
    const float* g_B2 = base + WS_B2;
    const float* g_C2 = base + WS_C2;
    const float* RA  = base + WS_RA;
    const float* RD  = base + WS_RD;
    const float* RAT = base + WS_RAT;
    const float* RDT = base + WS_RDT;

    const int pi = posmap[i];
    const float acti = act[i];
    const size_t rowoff = ((size_t)b*NDIM + i)*NDIM;
    const size_t seg = (size_t)BATCH*NDIM*NDIM;

    int4   p4  = ((const int4*)posmap)[lane];
    float4 aj4 = ((const float4*)act)[lane];
    int   pm[4] = {p4.x, p4.y, p4.z, p4.w};
    float aj[4] = {aj4.x, aj4.y, aj4.z, aj4.w};

    float a[4], arec[4], dv[4], rv[4];

    if (pi < 0) {
        const float* rat = RAT + (size_t)i*64;   // 256 B, L1-hot per half-block
        const float* rdt = RDT + (size_t)i*64;
        f4 v = __builtin_nontemporal_load((const f4*)(A + rowoff) + lane);
        a[0]=v.x; a[1]=v.y; a[2]=v.z; a[3]=v.w;
        #pragma unroll
        for (int c = 0; c < 4; ++c) {
            int pj = pm[c];
            if (pj >= 0) a[c] = rat[pj];
            float mv = (i == j0 + c) ? 1.f : acti * aj[c];
            dv[c] = a[c] * mv;
            arec[c] = (pj < 0) ? dv[c] : rdt[pj];
            rv[c] = (i == j0 + c) ? 1.f : 0.f;
        }
    } else {
        f4 v = ((const f4*)(RA + (size_t)pi*NDIM))[lane];
        f4 w = ((const f4*)(RD + (size_t)pi*NDIM))[lane];
        a[0]=v.x; a[1]=v.y; a[2]=v.z; a[3]=v.w;
        arec[0]=w.x; arec[1]=w.y; arec[2]=w.z; arec[3]=w.w;
        #pragma unroll
        for (int c = 0; c < 4; ++c) {
            int pj = pm[c];
            if (pj >= 0) {
                a[c]    = g_B2[pi*64 + pj];
                arec[c] = g_C2[pi*64 + pj];
                rv[c]   = g_W[pi*64 + pj];
            } else {
                rv[c] = 0.f;
            }
            float mv = (i == j0 + c) ? 1.f : acti * aj[c];
            dv[c] = a[c] * mv;
        }
    }

    f4 o0; o0.x = arec[0]; o0.y = arec[1]; o0.z = arec[2]; o0.w = arec[3];
    f4 o1; o1.x = rv[0];   o1.y = rv[1];   o1.z = rv[2];   o1.w = rv[3];
    f4 o2; o2.x = dv[0];   o2.y = dv[1];   o2.z = dv[2];   o2.w = dv[3];
    __builtin_nontemporal_store(o0, (f4*)(out + rowoff) + lane);
    __builtin_nontemporal_store(o1, (f4*)(out + seg + rowoff) + lane);
    __builtin_nontemporal_store(o2, (f4*)(out + 2*seg + rowoff) + lane);
}

extern "C" void kernel_launch(void* const* d_in, const int* in_sizes, int n_in,
                              void* d_out, int out_size, void* d_ws, size_t ws_size,
                              hipStream_t stream) {
    const float* A       = (const float*)d_in[0];
    const float* O       = (const float*)d_in[1];
    const int*   indices = (const int*)d_in[2];
    const int*   wavelet = (const int*)d_in[3];
    float* ws  = (float*)d_ws;   // needs ~18.5 MB
    float* out = (float*)d_out;

    k_prep<<<dim3(BATCH, 9), 256, 0, stream>>>(A, O, indices, wavelet, ws);
    k_big <<<dim3(NDIM/2, BATCH), 256, 0, stream>>>(A, ws, out);
}